// Round 7
// baseline (68.874 us; speedup 1.0000x reference)
//
#include <hip/hip_runtime.h>
#include <math.h>

#define NN   8
#define INCH 32
#define INN  50000
#define OUTC 64
#define OUTN 8192
#define DD   32
#define CC   256    // NN*INCH
#define NCK  8      // j-chunks (== #XCDs)
#define CHUNK (INN / NCK)   // 6250 rows = 3.2 MB bf16 -> fits one XCD's 4MB L2

typedef unsigned short ushortT;

__device__ __forceinline__ unsigned f2bf_u(float f) {
  unsigned u = __float_as_uint(f);
  return (u + 0x7FFFu + ((u >> 16) & 1u)) >> 16;   // round-nearest-even
}
__device__ __forceinline__ float bf2f(ushortT b) {
  return __uint_as_float(((unsigned)b) << 16);
}

// Kernel 1: yT[j][c] bf16, NATURAL layout (slot = c). Reads: 8 lanes per row -> 128B segments.
__global__ __launch_bounds__(256) void prep_kernel(
    const float* __restrict__ x, const float* __restrict__ nf, ushortT* __restrict__ yT) {
  __shared__ float tile[CC][33];   // stride 33 words: <=2-way banks all phases
  const int t = threadIdx.x;
  const int j0 = blockIdx.x * 32;
  const int jmax = min(32, INN - j0);   // 50000 = 1562*32 + 16

  const int q  = t & 7;    // j-quad within window
  const int r0 = t >> 3;   // row within 32-row group

  if (q * 4 < jmax) {
    const float4 nv = *(const float4*)(nf + (size_t)r0 * INN + j0 + 4 * q);  // loop-invariant
    #pragma unroll
    for (int p = 0; p < 8; ++p) {
      const int c = (p << 5) + r0;
      const float4 xv = *(const float4*)(x + (size_t)c * INN + j0 + 4 * q);
      float4 pr;
      pr.x = xv.x * nv.x; pr.y = xv.y * nv.y; pr.z = xv.z * nv.z; pr.w = xv.w * nv.w;
      *(float4*)&tile[c][4 * q] = pr;   // bank (r0+4q)%32 -> <=2-way
    }
  }
  __syncthreads();

  // store natural: lane packs c={2l,2l+1}(+128e) into dwords; 256B per wave-instr
  const int lane = t & 63;
  const int wave = t >> 6;
  #pragma unroll
  for (int r = 0; r < 8; ++r) {
    const int jl = wave * 8 + r;
    if (jl < jmax) {
      unsigned* dst = (unsigned*)(yT + (size_t)(j0 + jl) * CC);
      #pragma unroll
      for (int e = 0; e < 2; ++e) {
        const int c0 = 128 * e + 2 * lane;
        // LDS read bank (2*lane + jl)%32 -> 2-way (free)
        const unsigned lo = f2bf_u(tile[c0][jl]);
        const unsigned hi = f2bf_u(tile[c0 + 1][jl]);
        dst[lane + 64 * e] = lo | (hi << 16);
      }
    }
  }
}

// Kernel 2: j-chunked gather. block b: chunk ck=b%8 (-> same-XCD L2 locality under
// round-robin dispatch), o-slice b/8. Wave handles 16 o's as 8 pairs; lane-parallel
// in-range filter via ballot, full-wave 512B row gathers with SGPR row base.
// Writes partial max (-inf if no entry) to red_part[ck][o][c] bf16, nontemporal.
__global__ __launch_bounds__(256) void gather_kernel(
    const ushortT* __restrict__ yT, const int* __restrict__ A, ushortT* __restrict__ redp) {
  const int t = threadIdx.x;
  const int lane = t & 63;
  const int wave = t >> 6;
  const int ck = blockIdx.x & 7;
  const int ob = blockIdx.x >> 3;
  const int jlo = ck * CHUNK, jhi = jlo + CHUNK;
  const int o0 = ob * 64 + wave * 16;

  #pragma unroll
  for (int p = 0; p < 8; ++p) {
    const int opair = o0 + 2 * p;
    // lanes 0-31: d of o=opair; lanes 32-63: d of o=opair+1 (256B coalesced)
    const int vidx = A[(size_t)opair * DD + lane];
    const unsigned long long bal = __ballot(vidx >= jlo && vidx < jhi);
    unsigned mlo = (unsigned)bal;
    unsigned mhi = (unsigned)(bal >> 32);

    float a0 = -INFINITY, a1 = -INFINITY, a2 = -INFINITY, a3 = -INFINITY;
    float b0 = -INFINITY, b1 = -INFINITY, b2 = -INFINITY, b3 = -INFINITY;

    while (mlo) {
      const int bpos = __builtin_ctz(mlo); mlo &= mlo - 1;
      const int sidx = __builtin_amdgcn_readlane(vidx, bpos);   // uniform -> SGPR base
      const uint2 v = *(const uint2*)(yT + (size_t)sidx * CC + 4 * lane);  // 512B/wave
      a0 = fmaxf(a0, __uint_as_float(v.x << 16));
      a1 = fmaxf(a1, __uint_as_float(v.x & 0xffff0000u));
      a2 = fmaxf(a2, __uint_as_float(v.y << 16));
      a3 = fmaxf(a3, __uint_as_float(v.y & 0xffff0000u));
    }
    while (mhi) {
      const int bpos = __builtin_ctz(mhi); mhi &= mhi - 1;
      const int sidx = __builtin_amdgcn_readlane(vidx, bpos + 32);
      const uint2 v = *(const uint2*)(yT + (size_t)sidx * CC + 4 * lane);
      b0 = fmaxf(b0, __uint_as_float(v.x << 16));
      b1 = fmaxf(b1, __uint_as_float(v.x & 0xffff0000u));
      b2 = fmaxf(b2, __uint_as_float(v.y << 16));
      b3 = fmaxf(b3, __uint_as_float(v.y & 0xffff0000u));
    }

    // natural store c=4l..4l+3; f2bf exact (inputs already bf16; f2bf(-inf)=0xFF80)
    const unsigned long long ua =
        (unsigned long long)(f2bf_u(a0) | (f2bf_u(a1) << 16)) |
        ((unsigned long long)(f2bf_u(a2) | (f2bf_u(a3) << 16)) << 32);
    const unsigned long long ub =
        (unsigned long long)(f2bf_u(b0) | (f2bf_u(b1) << 16)) |
        ((unsigned long long)(f2bf_u(b2) | (f2bf_u(b3) << 16)) << 32);
    unsigned long long* r0 =
        (unsigned long long*)(redp + ((size_t)ck * OUTN + opair) * CC) + lane;
    unsigned long long* r1 =
        (unsigned long long*)(redp + ((size_t)ck * OUTN + opair + 1) * CC) + lane;
    __builtin_nontemporal_store(ua, r0);   // don't evict the chunk from L2
    __builtin_nontemporal_store(ub, r1);
  }
}

// Kernel 3: merge 8 partials + out[n,k,o] = sum_i red[o][n*32+i]*ft[i][k] + bias[k][o]
__global__ __launch_bounds__(256) void out_kernel(
    const ushortT* __restrict__ redp, const float* __restrict__ ft,
    const float* __restrict__ bias, float* __restrict__ out) {
  __shared__ float rtile[64][65];   // [o_local][c_local], pad 65 -> <=2-way
  __shared__ float ftl[32][64];
  const int t = threadIdx.x;
  const int lane = t & 63;
  const int wave = t >> 6;
  const int np = blockIdx.x >> 7;   // 0..3
  const int ot = blockIdx.x & 127;  // 0..127
  const int o0 = ot * 64;
  const int c0 = np * 64;

  #pragma unroll
  for (int q = 0; q < 8; ++q) {
    const int idx = q * 256 + t;
    ftl[idx >> 6][idx & 63] = ft[idx];
  }
  // merge-load: thread covers 8 c's of a row across all 8 chunks
  #pragma unroll
  for (int i = 0; i < 2; ++i) {
    const int r = (t >> 3) + 32 * i;
    const int g = t & 7;
    float vm[8];
    #pragma unroll
    for (int u = 0; u < 8; ++u) vm[u] = -INFINITY;
    #pragma unroll
    for (int ck = 0; ck < NCK; ++ck) {
      const ushort4* src =
          (const ushort4*)(redp + ((size_t)ck * OUTN + o0 + r) * CC + c0 + g * 8);
      const ushort4 v0 = src[0];
      const ushort4 v1 = src[1];
      vm[0] = fmaxf(vm[0], bf2f(v0.x)); vm[1] = fmaxf(vm[1], bf2f(v0.y));
      vm[2] = fmaxf(vm[2], bf2f(v0.z)); vm[3] = fmaxf(vm[3], bf2f(v0.w));
      vm[4] = fmaxf(vm[4], bf2f(v1.x)); vm[5] = fmaxf(vm[5], bf2f(v1.y));
      vm[6] = fmaxf(vm[6], bf2f(v1.z)); vm[7] = fmaxf(vm[7], bf2f(v1.w));
    }
    float* dst = &rtile[r][g * 8];    // bank (r+8g+u)%32 -> conflict-free per u
    #pragma unroll
    for (int u = 0; u < 8; ++u) dst[u] = vm[u];
  }
  __syncthreads();

  const int n  = np * 2 + (wave & 1);
  const int kh = (wave >> 1) * 32;
  const int cb = (wave & 1) * 32;

  float rv[32];
  #pragma unroll
  for (int i = 0; i < 32; ++i) rv[i] = rtile[lane][cb + i];   // 2-way

  float acc[32];
  #pragma unroll
  for (int kk = 0; kk < 32; ++kk) acc[kk] = 0.f;
  #pragma unroll
  for (int i = 0; i < 32; ++i) {
    #pragma unroll
    for (int kk = 0; kk < 32; ++kk)
      acc[kk] += rv[i] * ftl[i][kh + kk];   // uniform addr -> broadcast
  }

  float* op = out + (size_t)n * OUTC * OUTN + o0 + lane;
  const float* bp = bias + o0 + lane;
  #pragma unroll
  for (int kk = 0; kk < 32; ++kk) {
    const int k = kh + kk;
    op[(size_t)k * OUTN] = acc[kk] + bp[(size_t)k * OUTN];   // 256B-contiguous stores
  }
}

extern "C" void kernel_launch(void* const* d_in, const int* in_sizes, int n_in,
                              void* d_out, int out_size, void* d_ws, size_t ws_size,
                              hipStream_t stream) {
  const float* x    = (const float*)d_in[0];
  const float* nf   = (const float*)d_in[1];
  const float* ft   = (const float*)d_in[2];
  const float* bias = (const float*)d_in[3];
  const int*   A    = (const int*)d_in[4];
  float* out = (float*)d_out;

  ushortT* yT   = (ushortT*)d_ws;                                  // 50000*256*2 = 25.6 MB
  ushortT* redp = (ushortT*)((char*)d_ws + (size_t)INN * CC * 2);  // 8*8192*256*2 = 33.6 MB

  hipLaunchKernelGGL(prep_kernel,   dim3((INN + 31) / 32), dim3(256), 0, stream, x, nf, yT);
  hipLaunchKernelGGL(gather_kernel, dim3((OUTN / 64) * NCK), dim3(256), 0, stream, yT, A, redp);
  hipLaunchKernelGGL(out_kernel,    dim3(512),             dim3(256), 0, stream, redp, ft, bias, out);
}